// Round 1
// baseline (779.329 us; speedup 1.0000x reference)
//
#include <hip/hip_runtime.h>
#include <hip/hip_bf16.h>

#define XDIM 128
#define YDIM 512

typedef __bf16 bf16x8 __attribute__((ext_vector_type(8)));
typedef float  floatx4 __attribute__((ext_vector_type(4)));

// Block: 256 threads = 4 waves. Block tile: 32 rows x 512 cols (all of Y).
// Wave w owns cols [w*128, w*128+128). All waves share the same 32 A-rows (L1 hits).
// K=128 = 4 MFMA k-steps of 32, fully unrolled; A fragments pinned in registers.
// No LDS: A and B fragments for mfma_f32_16x16x32_bf16 need 8 consecutive k per
// lane, which row-major mean/logvar/W provide directly (m97 gemm_bt layout).
__global__ __launch_bounds__(256, 2)
void decoder_mfma_kernel(const float* __restrict__ mean,
                         const float* __restrict__ logvar,
                         const float* __restrict__ W,
                         const float* __restrict__ bias,
                         float* __restrict__ out_mean,
                         float* __restrict__ out_logv)
{
    const int tid   = threadIdx.x;
    const int lane  = tid & 63;
    const int wv    = tid >> 6;
    const int laneM = lane & 15;          // m (A) / n (B) / col (C)
    const int laneK = (lane >> 4) * 8;    // k-chunk base: 0,8,16,24

    const int row_base = blockIdx.x * 32;
    const int col_base = wv * 128;

    // ---- A fragments: mean and exp(logvar); 2 row-tiles x 4 k-steps ----
    bf16x8 aM[2][4], aV[2][4];
#pragma unroll
    for (int rt = 0; rt < 2; ++rt) {
        const int r = row_base + rt * 16 + laneM;
        const float* mrow = mean   + (size_t)r * XDIM + laneK;
        const float* lrow = logvar + (size_t)r * XDIM + laneK;
#pragma unroll
        for (int ks = 0; ks < 4; ++ks) {
            floatx4 m0 = *(const floatx4*)(mrow + ks * 32);
            floatx4 m1 = *(const floatx4*)(mrow + ks * 32 + 4);
            floatx4 l0 = *(const floatx4*)(lrow + ks * 32);
            floatx4 l1 = *(const floatx4*)(lrow + ks * 32 + 4);
            bf16x8 am, av;
#pragma unroll
            for (int j = 0; j < 4; ++j) {
                am[j]     = (__bf16)m0[j];
                am[j + 4] = (__bf16)m1[j];
                av[j]     = (__bf16)__expf(l0[j]);
                av[j + 4] = (__bf16)__expf(l1[j]);
            }
            aM[rt][ks] = am;
            aV[rt][ks] = av;
        }
    }

    floatx4 accM[2][8], accV[2][8];
#pragma unroll
    for (int rt = 0; rt < 2; ++rt)
#pragma unroll
        for (int ct = 0; ct < 8; ++ct) {
            accM[rt][ct] = (floatx4){0.f, 0.f, 0.f, 0.f};
            accV[rt][ct] = (floatx4){0.f, 0.f, 0.f, 0.f};
        }

    // ---- K-loop: B fragments straight from global W; W^2 frag = square in VALU ----
#pragma unroll
    for (int ks = 0; ks < 4; ++ks) {
#pragma unroll
        for (int ct = 0; ct < 8; ++ct) {
            const float* wrow = W + (size_t)(col_base + ct * 16 + laneM) * XDIM
                                  + ks * 32 + laneK;
            floatx4 w0 = *(const floatx4*)(wrow);
            floatx4 w1 = *(const floatx4*)(wrow + 4);
            bf16x8 bw, bs;
#pragma unroll
            for (int j = 0; j < 4; ++j) {
                bw[j]     = (__bf16)w0[j];
                bw[j + 4] = (__bf16)w1[j];
                bs[j]     = (__bf16)(w0[j] * w0[j]);
                bs[j + 4] = (__bf16)(w1[j] * w1[j]);
            }
#pragma unroll
            for (int rt = 0; rt < 2; ++rt) {
                accM[rt][ct] = __builtin_amdgcn_mfma_f32_16x16x32_bf16(
                                   aM[rt][ks], bw, accM[rt][ct], 0, 0, 0);
                accV[rt][ct] = __builtin_amdgcn_mfma_f32_16x16x32_bf16(
                                   aV[rt][ks], bs, accV[rt][ct], 0, 0, 0);
            }
        }
    }

    // ---- epilogue: bias add / log, scalar stores (4 rows x 16-col 64B segments) ----
    // C/D layout (m89-verified): col = lane&15, row = (lane>>4)*4 + reg.
#pragma unroll
    for (int ct = 0; ct < 8; ++ct) {
        const int col = col_base + ct * 16 + laneM;
        const float bv = bias[col];
#pragma unroll
        for (int rt = 0; rt < 2; ++rt) {
            const int r0 = row_base + rt * 16 + (lane >> 4) * 4;
#pragma unroll
            for (int i = 0; i < 4; ++i) {
                out_mean[(size_t)(r0 + i) * YDIM + col] = accM[rt][ct][i] + bv;
                out_logv[(size_t)(r0 + i) * YDIM + col] = __logf(accV[rt][ct][i]);
            }
        }
    }
}

extern "C" void kernel_launch(void* const* d_in, const int* in_sizes, int n_in,
                              void* d_out, int out_size, void* d_ws, size_t ws_size,
                              hipStream_t stream)
{
    const float* mean   = (const float*)d_in[0];
    const float* logvar = (const float*)d_in[1];
    const float* W      = (const float*)d_in[2];
    const float* bias   = (const float*)d_in[3];

    const int batch = in_sizes[0] / XDIM;   // 131072
    float* out_mean = (float*)d_out;
    float* out_logv = (float*)d_out + (size_t)batch * YDIM;

    dim3 grid(batch / 32);
    dim3 block(256);
    hipLaunchKernelGGL(decoder_mfma_kernel, grid, block, 0, stream,
                       mean, logvar, W, bias, out_mean, out_logv);
}